// Round 2
// baseline (3000.703 us; speedup 1.0000x reference)
//
#include <hip/hip_runtime.h>
#include <math.h>

#define B 16
#define CH 128
#define DIM 128
#define MODES 32
#define NLAYERS 4
#define PROJ 128
#define U 64            // stored kx modes: u<32 -> kx=u ; u>=32 -> kx=u+64 (96..127)
#define KY 32
#define NMODE (U*KY)    // 2048
#define N2 (DIM*DIM)    // 16384
#define PG 8            // p-groups in idft
#define PPG (PROJ/PG)   // 16 p per group

// ---------------- K1: zf corners of rfft2(z), per batch ----------------
__global__ __launch_bounds__(256) void k_zf(const float* __restrict__ z,
                                            float* __restrict__ zfr, float* __restrict__ zfi) {
  __shared__ float zs[N2];                  // 64 KB
  __shared__ float twc[DIM], tws[DIM];      // 1 KB
  __shared__ float t1r[DIM][KY], t1i[DIM][KY]; // 32 KB
  int b = blockIdx.x, t = threadIdx.x;
  for (int idx = t * 4; idx < N2; idx += 256 * 4)
    *(float4*)&zs[idx] = *(const float4*)&z[b * N2 + idx];
  if (t < 128) {
    float ang = (float)(2.0 * M_PI) * (float)t / 128.0f;
    twc[t] = cosf(ang); tws[t] = sinf(ang);
  }
  __syncthreads();
  for (int idx = t; idx < DIM * KY; idx += 256) {
    int x = idx >> 5, ky = idx & 31;
    float ar = 0.f, ai = 0.f;
    for (int y = 0; y < DIM; ++y) {
      float v = zs[x * DIM + y];
      int tt = (ky * y) & 127;
      ar += v * twc[tt];
      ai -= v * tws[tt];
    }
    t1r[x][ky] = ar; t1i[x][ky] = ai;
  }
  __syncthreads();
  for (int idx = t; idx < U * KY; idx += 256) {
    int u = idx >> 5, ky = idx & 31;
    int kx = (u < 32) ? u : (u + 64);
    float ar = 0.f, ai = 0.f;
    for (int x = 0; x < DIM; ++x) {
      int tt = (kx * x) & 127;
      float c = twc[tt], s = tws[tt];
      float vr = t1r[x][ky], vi = t1i[x][ky];
      ar += vr * c + vi * s;
      ai += vi * c - vr * s;
    }
    zfr[b * NMODE + idx] = ar;
    zfi[b * NMODE + idx] = ai;
  }
}

// ---------------- K2: lift in spectral space (float2 out) ----------------
__global__ __launch_bounds__(256) void k_lift(const float* __restrict__ zfr, const float* __restrict__ zfi,
                                              const float* __restrict__ lw, const float* __restrict__ lb,
                                              float2* __restrict__ vcout) {
  int idx = blockIdx.x * 256 + threadIdx.x;   // B*CH*NMODE
  if (idx >= B * CH * NMODE) return;
  int m = idx & (NMODE - 1);
  int c = (idx >> 11) & 127;
  int b = idx >> 18;
  float w = lw[c];
  float re = w * zfr[b * NMODE + m];
  float im = w * zfi[b * NMODE + m];
  if (m == 0) re += 16384.f * lb[c];
  vcout[idx] = make_float2(re, im);
}

// ---------------- K3: spectral einsum, one layer ----------------
// grid = 1024: u=((bid&7)<<3)|((bid>>3)&7) (same-u blocks share an XCD), ot=bid>>6 (8 o's each)
__global__ __launch_bounds__(256) void k_spec(const float2* __restrict__ vc,
                                              const float* __restrict__ wr1, const float* __restrict__ wi1,
                                              const float* __restrict__ wr2, const float* __restrict__ wi2,
                                              float2* __restrict__ oc) {
  int bid = blockIdx.x;
  int u = ((bid & 7) << 3) | ((bid >> 3) & 7);
  int ot = bid >> 6;                        // 0..15
  int kxw = u & 31;
  const float* wr = (u >> 5) ? wr2 : wr1;
  const float* wi = (u >> 5) ? wi2 : wi1;
  int t = threadIdx.x;
  int ky = t & 31, bh = (t >> 5) & 1, q = t >> 6;   // q = wave id 0..3
  __shared__ float2 Vc[8][KY][17];          // ~34.8 KB
  float accR[2][8] = {}, accI[2][8] = {};
  const int obase = ot * 8 + q * 2;
  for (int ic = 0; ic < CH; ic += 8) {
    __syncthreads();
    for (int e = t; e < 8 * 16 * KY; e += 256) {
      int kyy = e & 31;
      int bb = (e >> 5) & 15;
      int il = e >> 9;
      Vc[il][kyy][bb] = vc[(((size_t)bb * CH + (ic + il)) * U + u) * KY + kyy];
    }
    __syncthreads();
    #pragma unroll
    for (int il = 0; il < 8; ++il) {
      int i = ic + il;
      float wrv[2], wiv[2];
      #pragma unroll
      for (int j = 0; j < 2; ++j) {
        int off = ((i * CH + obase + j) * MODES + kxw) * MODES + ky;
        wrv[j] = wr[off]; wiv[j] = wi[off];
      }
      float2 xv[8];
      #pragma unroll
      for (int k = 0; k < 8; ++k) xv[k] = Vc[il][ky][bh * 8 + k];
      #pragma unroll
      for (int j = 0; j < 2; ++j)
        #pragma unroll
        for (int k = 0; k < 8; ++k) {
          accR[j][k] += wrv[j] * xv[k].x - wiv[j] * xv[k].y;
          accI[j][k] += wrv[j] * xv[k].y + wiv[j] * xv[k].x;
        }
    }
  }
  #pragma unroll
  for (int j = 0; j < 2; ++j)
    #pragma unroll
    for (int k = 0; k < 8; ++k) {
      int o = obase + j, b = bh * 8 + k;
      oc[(((size_t)b * CH + o) * U + u) * KY + ky] = make_float2(accR[j][k], accI[j][k]);
    }
}

// ---------------- K3b: Hermitian projection of ky=0 column ----------------
__global__ __launch_bounds__(256) void k_proj0(float2* __restrict__ vc) {
  int idx = blockIdx.x * 256 + threadIdx.x;   // B*CH*33
  if (idx >= B * CH * 33) return;
  int pi = idx % 33;
  int bc = idx / 33;
  float2* base = vc + (size_t)bc * NMODE;
  if (pi == 0) {
    base[0].y = 0.f;
  } else if (pi == 32) {
    base[32 * KY].x *= 0.5f;
    base[32 * KY].y *= 0.5f;
  } else {
    int ua = pi, ub = 64 - pi;
    float2 a = base[ua * KY], b2 = base[ub * KY];
    base[ua * KY] = make_float2(0.5f * (a.x + b2.x), 0.5f * (a.y - b2.y));
    base[ub * KY] = make_float2(0.5f * (b2.x + a.x), 0.5f * (b2.y - a.y));
  }
}

// ---------------- K4: pw1 in spectral space (float2 io) ----------------
__global__ __launch_bounds__(256) void k_pw1(const float2* __restrict__ xc,
                                             const float* __restrict__ pw1,
                                             float2* __restrict__ hc) {
  __shared__ float wT[CH][CH + 1];            // [c][p] padded
  int bid = blockIdx.x;
  int b = bid >> 5, jt = bid & 31;
  int t = threadIdx.x;
  for (int e = t; e < CH * CH; e += 256) {
    int p = e >> 7, c = e & 127;
    wT[c][p] = pw1[e];
  }
  __syncthreads();
  int tx = t & 15, ty = t >> 4;
  int j0 = jt * 64 + tx * 4;
  float accR[4][8] = {}, accI[4][8] = {};
  for (int c = 0; c < CH; ++c) {
    const float4* x4 = (const float4*)&xc[((size_t)b * CH + c) * NMODE + j0];
    float4 v0 = x4[0], v1 = x4[1];
    float xrv[4] = {v0.x, v0.z, v1.x, v1.z};
    float xiv[4] = {v0.y, v0.w, v1.y, v1.w};
    float w[8];
    #pragma unroll
    for (int pp = 0; pp < 8; ++pp) w[pp] = wT[c][ty * 8 + pp];
    #pragma unroll
    for (int jj = 0; jj < 4; ++jj)
      #pragma unroll
      for (int pp = 0; pp < 8; ++pp) {
        accR[jj][pp] += w[pp] * xrv[jj];
        accI[jj][pp] += w[pp] * xiv[jj];
      }
  }
  #pragma unroll
  for (int pp = 0; pp < 8; ++pp) {
    int p = ty * 8 + pp;
    float4* o4 = (float4*)&hc[((size_t)b * CH + p) * NMODE + j0];
    o4[0] = make_float4(accR[0][pp], accI[0][pp], accR[1][pp], accI[1][pp]);
    o4[1] = make_float4(accR[2][pp], accI[2][pp], accR[3][pp], accI[3][pp]);
  }
}

// ---------------- K5: fused iDFT + bias + gelu + pw2, p-group partials ----------------
// grid = B * PG * 16 strips = 2048 blocks. Per-thread register cache of y-twiddles.
__global__ __launch_bounds__(256) void k_idft_partial(const float2* __restrict__ hc,
                                                      const float* __restrict__ pb1,
                                                      const float* __restrict__ pw2,
                                                      float* __restrict__ partial) {
  __shared__ float2 tw[DIM];                  // (cos, sin) 1 KB
  __shared__ float2 hfs[NMODE];               // 16 KB
  __shared__ float2 sbuf[KY][9];              // padded, ~2.3 KB
  int bid = blockIdx.x;
  int b = bid >> 7, pg = (bid >> 4) & 7, xs = bid & 15;
  int x0 = xs * 8;
  int t = threadIdx.x;
  if (t < 128) {
    float ang = (float)(2.0 * M_PI) * (float)t / 128.0f;
    tw[t] = make_float2(cosf(ang), sinf(ang));
  }
  __syncthreads();
  // phase-B ownership: one y per thread, 4 x's (strip rows k*2+xh)
  int y = t & 127, xh = t >> 7;
  float Cr[KY], Sr[KY];
  #pragma unroll
  for (int ky = 0; ky < KY; ++ky) {
    float2 w = tw[(ky * y) & 127];
    float wk = (ky == 0) ? 1.f : 2.f;
    Cr[ky] = wk * w.x;
    Sr[ky] = -wk * w.y;
  }
  // phase-A ownership
  int kyA = t & 31, xiA = t >> 5;
  int xA = x0 + xiA;
  float res[4] = {0.f, 0.f, 0.f, 0.f};
  for (int pp = 0; pp < PPG; ++pp) {
    int p = pg * PPG + pp;
    __syncthreads();
    {
      const float4* src = (const float4*)&hc[((size_t)b * CH + p) * NMODE];
      float4* dst = (float4*)hfs;
      for (int e = t; e < NMODE / 2; e += 256) dst[e] = src[e];
    }
    __syncthreads();
    // phase A: s[ky][xi] = sum_u hf[u][ky] e^{+2pi i kx x/128}
    {
      float ar = 0.f, ai = 0.f;
      #pragma unroll
      for (int uu = 0; uu < U; ++uu) {
        int kx = (uu < 32) ? uu : (uu + 64);
        int tt = (kx * xA) & 127;
        float2 w = tw[tt];
        float2 v = hfs[uu * KY + kyA];
        ar += v.x * w.x - v.y * w.y;
        ai += v.x * w.y + v.y * w.x;
      }
      sbuf[kyA][xiA] = make_float2(ar, ai);
    }
    __syncthreads();
    // phase B: per-pixel reduce over ky with register twiddles, gelu, pw2
    float pb = pb1[p], pw = pw2[p];
    #pragma unroll
    for (int k = 0; k < 4; ++k) {
      int xi = k * 2 + xh;
      float acc = 0.f;
      #pragma unroll
      for (int ky = 0; ky < KY; ++ky) {
        float2 sv = sbuf[ky][xi];
        acc += sv.x * Cr[ky] + sv.y * Sr[ky];
      }
      float h = acc * (1.f / 16384.f) + pb;
      float g = 0.5f * h * (1.f + tanhf(0.7978845608028654f * (h + 0.044715f * h * h * h)));
      res[k] += pw * g;
    }
  }
  #pragma unroll
  for (int k = 0; k < 4; ++k) {
    int x = x0 + k * 2 + xh;
    partial[((size_t)pg * B + b) * N2 + x * DIM + y] = res[k];
  }
}

// ---------------- K6: reduce p-group partials + pb2 ----------------
__global__ __launch_bounds__(256) void k_reduce(const float* __restrict__ partial,
                                                const float* __restrict__ pb2,
                                                float* __restrict__ outp) {
  int idx = blockIdx.x * 256 + threadIdx.x;   // B*N2 = 262144
  if (idx >= B * N2) return;
  float s = pb2[0];
  #pragma unroll
  for (int pg = 0; pg < PG; ++pg) s += partial[(size_t)pg * B * N2 + idx];
  outp[idx] = s;
}

extern "C" void kernel_launch(void* const* d_in, const int* in_sizes, int n_in,
                              void* d_out, int out_size, void* d_ws, size_t ws_size,
                              hipStream_t stream) {
  const float* z   = (const float*)d_in[0];
  const float* lw  = (const float*)d_in[1];
  const float* lb  = (const float*)d_in[2];
  const float* wr1 = (const float*)d_in[3];
  const float* wi1 = (const float*)d_in[4];
  const float* wr2 = (const float*)d_in[5];
  const float* wi2 = (const float*)d_in[6];
  const float* pw1 = (const float*)d_in[7];
  const float* pb1 = (const float*)d_in[8];
  const float* pw2 = (const float*)d_in[9];
  const float* pb2 = (const float*)d_in[10];
  float* out = (float*)d_out;
  float* ws = (float*)d_ws;

  // ws layout: zfr/zfi (2*32768 floats), Ac/Bc interleaved complex ping-pong
  // (2 * 4,194,304 float2). Total ~67.4 MB. partial (8 MB) aliases the dead
  // ping buffer after k_pw1.
  float* zfr = ws;
  float* zfi = zfr + 32768;
  float2* Ac = (float2*)(ws + 65536);
  float2* Bc = Ac + (size_t)B * CH * NMODE;

  k_zf<<<B, 256, 0, stream>>>(z, zfr, zfi);
  k_lift<<<(B * CH * NMODE) / 256, 256, 0, stream>>>(zfr, zfi, lw, lb, Ac);

  const size_t WSTRIDE = (size_t)CH * CH * MODES * MODES;
  float2 *ir = Ac, *oc = Bc;
  for (int l = 0; l < NLAYERS; ++l) {
    k_spec<<<1024, 256, 0, stream>>>(ir,
                                     wr1 + l * WSTRIDE, wi1 + l * WSTRIDE,
                                     wr2 + l * WSTRIDE, wi2 + l * WSTRIDE,
                                     oc);
    if (l < NLAYERS - 1)
      k_proj0<<<(B * CH * 33 + 255) / 256, 256, 0, stream>>>(oc);
    float2* tmp = ir; ir = oc; oc = tmp;
  }
  // ir = final spectral field; oc buffer is free -> holds hc
  k_pw1<<<512, 256, 0, stream>>>(ir, pw1, oc);
  // partial aliases ir (dead after k_pw1 reads complete; stream-ordered)
  float* partial = (float*)ir;
  k_idft_partial<<<B * PG * 16, 256, 0, stream>>>(oc, pb1, pw2, partial);
  k_reduce<<<(B * N2) / 256, 256, 0, stream>>>(partial, pb2, out);
}

// Round 3
// 999.239 us; speedup vs baseline: 3.0030x; 3.0030x over previous
//
#include <hip/hip_runtime.h>
#include <math.h>

#define B 16
#define CH 128
#define DIM 128
#define MODES 32
#define NLAYERS 4
#define PROJ 128
#define U 64            // stored kx modes: u<32 -> kx=u ; u>=32 -> kx=u+64 (96..127)
#define KY 32
#define NMODE (U*KY)    // 2048
#define N2 (DIM*DIM)    // 16384
#define PG 8            // p-groups in idft
#define PPG (PROJ/PG)   // 16 p per group

__device__ __forceinline__ void async16(const void* g, void* l) {
  __builtin_amdgcn_global_load_lds((const __attribute__((address_space(1))) unsigned int*)g,
                                   (__attribute__((address_space(3))) unsigned int*)l, 16, 0, 0);
}

// ---------------- K1: zf corners of rfft2(z), per batch ----------------
__global__ __launch_bounds__(256) void k_zf(const float* __restrict__ z,
                                            float* __restrict__ zfr, float* __restrict__ zfi) {
  __shared__ float zs[N2];                  // 64 KB
  __shared__ float twc[DIM], tws[DIM];      // 1 KB
  __shared__ float t1r[DIM][KY], t1i[DIM][KY]; // 32 KB
  int b = blockIdx.x, t = threadIdx.x;
  for (int idx = t * 4; idx < N2; idx += 256 * 4)
    *(float4*)&zs[idx] = *(const float4*)&z[b * N2 + idx];
  if (t < 128) {
    float ang = (float)(2.0 * M_PI) * (float)t / 128.0f;
    twc[t] = cosf(ang); tws[t] = sinf(ang);
  }
  __syncthreads();
  for (int idx = t; idx < DIM * KY; idx += 256) {
    int x = idx >> 5, ky = idx & 31;
    float ar = 0.f, ai = 0.f;
    for (int y = 0; y < DIM; ++y) {
      float v = zs[x * DIM + y];
      int tt = (ky * y) & 127;
      ar += v * twc[tt];
      ai -= v * tws[tt];
    }
    t1r[x][ky] = ar; t1i[x][ky] = ai;
  }
  __syncthreads();
  for (int idx = t; idx < U * KY; idx += 256) {
    int u = idx >> 5, ky = idx & 31;
    int kx = (u < 32) ? u : (u + 64);
    float ar = 0.f, ai = 0.f;
    for (int x = 0; x < DIM; ++x) {
      int tt = (kx * x) & 127;
      float c = twc[tt], s = tws[tt];
      float vr = t1r[x][ky], vi = t1i[x][ky];
      ar += vr * c + vi * s;
      ai += vi * c - vr * s;
    }
    zfr[b * NMODE + idx] = ar;
    zfi[b * NMODE + idx] = ai;
  }
}

// ---------------- K2: lift in spectral space (float2 out) ----------------
__global__ __launch_bounds__(256) void k_lift(const float* __restrict__ zfr, const float* __restrict__ zfi,
                                              const float* __restrict__ lw, const float* __restrict__ lb,
                                              float2* __restrict__ vcout) {
  int idx = blockIdx.x * 256 + threadIdx.x;   // B*CH*NMODE
  if (idx >= B * CH * NMODE) return;
  int m = idx & (NMODE - 1);
  int c = (idx >> 11) & 127;
  int b = idx >> 18;
  float w = lw[c];
  float re = w * zfr[b * NMODE + m];
  float im = w * zfi[b * NMODE + m];
  if (m == 0) re += 16384.f * lb[c];
  vcout[idx] = make_float2(re, im);
}

// ---------------- K3: spectral einsum, one layer ----------------
// grid = 512: u = ((bid&7)<<3)|((bid>>3)&7) (same-u blocks -> same XCD),
// rest = bid>>6: ot = rest&3 (32 o's), bh = rest>>2 (8 b's).
// Double-buffered async W/V staging, one barrier per i-chunk of 4.
__global__ __launch_bounds__(256, 2) void k_spec(const float2* __restrict__ vc,
                                                 const float* __restrict__ wr1, const float* __restrict__ wi1,
                                                 const float* __restrict__ wr2, const float* __restrict__ wi2,
                                                 float2* __restrict__ oc) {
  __shared__ float lW[2][2][4][32][32];     // [buf][arr r/i][i][o][ky] 64 KB
  __shared__ float2 lV[2][4][8][32];        // [buf][i][b][ky] 16 KB
  int bid = blockIdx.x;
  int u = ((bid & 7) << 3) | ((bid >> 3) & 7);
  int rest = bid >> 6;
  int o0 = (rest & 3) * 32;
  int b0 = (rest >> 2) * 8;
  int kxw = u & 31;
  const float* wr = (u >= 32) ? wr2 : wr1;
  const float* wi = (u >= 32) ? wi2 : wi1;
  int t = threadIdx.x;
  int ky = t & 31, oq = t >> 5;             // oq 0..7 -> 4 o's each
  int wv = t >> 6, lane = t & 63;
  float accR[4][8] = {}, accI[4][8] = {};

  // stage(chunk i0 -> buffer bf): 8 W issues + 2 V issues per wave
  #define STAGE(bf, i0)                                                              \
    {                                                                                \
      _Pragma("unroll")                                                              \
      for (int n = 0; n < 8; ++n) {                                                  \
        int unit = (wv * 8 + n) * 64 + lane;                                         \
        int arr = unit >> 10, rem = unit & 1023;                                     \
        int i_l = rem >> 8, o_l = (rem >> 3) & 31, kq = rem & 7;                     \
        const float* src = (arr ? wi : wr) +                                         \
          (((size_t)((i0) + i_l) * CH + o0 + o_l) * MODES + kxw) * MODES + kq * 4;   \
        async16(src, (char*)&lW[bf][0][0][0][0] + (size_t)(wv * 8 + n) * 1024);      \
      }                                                                              \
      _Pragma("unroll")                                                              \
      for (int n = 0; n < 2; ++n) {                                                  \
        int unit = (wv * 2 + n) * 64 + lane;                                         \
        int i_l = unit >> 7, b_l = (unit >> 4) & 7, kh = unit & 15;                  \
        const float2* src = vc + ((size_t)(b0 + b_l) * CH + ((i0) + i_l)) * NMODE +  \
                            u * KY + kh * 2;                                         \
        async16(src, (char*)&lV[bf][0][0][0] + (size_t)(wv * 2 + n) * 1024);         \
      }                                                                              \
    }

  STAGE(0, 0);
  for (int k = 0; k < 32; ++k) {
    int cur = k & 1;
    __syncthreads();                        // drains async loads of chunk k; prior reads done
    if (k + 1 < 32) STAGE(cur ^ 1, (k + 1) * 4);
    #pragma unroll
    for (int il = 0; il < 4; ++il) {
      float wrv[4], wiv[4];
      #pragma unroll
      for (int j = 0; j < 4; ++j) {
        wrv[j] = lW[cur][0][il][oq * 4 + j][ky];
        wiv[j] = lW[cur][1][il][oq * 4 + j][ky];
      }
      #pragma unroll
      for (int bb = 0; bb < 8; ++bb) {
        float2 v = lV[cur][il][bb][ky];
        #pragma unroll
        for (int j = 0; j < 4; ++j) {
          accR[j][bb] += wrv[j] * v.x - wiv[j] * v.y;
          accI[j][bb] += wrv[j] * v.y + wiv[j] * v.x;
        }
      }
    }
  }
  #undef STAGE
  #pragma unroll
  for (int j = 0; j < 4; ++j)
    #pragma unroll
    for (int bb = 0; bb < 8; ++bb) {
      int o = o0 + oq * 4 + j, b = b0 + bb;
      oc[(((size_t)b * CH + o) * U + u) * KY + ky] = make_float2(accR[j][bb], accI[j][bb]);
    }
}

// ---------------- K3b: Hermitian projection of ky=0 column ----------------
__global__ __launch_bounds__(256) void k_proj0(float2* __restrict__ vc) {
  int idx = blockIdx.x * 256 + threadIdx.x;   // B*CH*33
  if (idx >= B * CH * 33) return;
  int pi = idx % 33;
  int bc = idx / 33;
  float2* base = vc + (size_t)bc * NMODE;
  if (pi == 0) {
    base[0].y = 0.f;
  } else if (pi == 32) {
    base[32 * KY].x *= 0.5f;
    base[32 * KY].y *= 0.5f;
  } else {
    int ua = pi, ub = 64 - pi;
    float2 a = base[ua * KY], b2 = base[ub * KY];
    base[ua * KY] = make_float2(0.5f * (a.x + b2.x), 0.5f * (a.y - b2.y));
    base[ub * KY] = make_float2(0.5f * (b2.x + a.x), 0.5f * (b2.y - a.y));
  }
}

// ---------------- K4: pw1 in spectral space (float2 io) ----------------
__global__ __launch_bounds__(256) void k_pw1(const float2* __restrict__ xc,
                                             const float* __restrict__ pw1,
                                             float2* __restrict__ hc) {
  __shared__ float wT[CH][CH + 1];            // [c][p] padded
  int bid = blockIdx.x;
  int b = bid >> 5, jt = bid & 31;
  int t = threadIdx.x;
  for (int e = t; e < CH * CH; e += 256) {
    int p = e >> 7, c = e & 127;
    wT[c][p] = pw1[e];
  }
  __syncthreads();
  int tx = t & 15, ty = t >> 4;
  int j0 = jt * 64 + tx * 4;
  float accR[4][8] = {}, accI[4][8] = {};
  for (int c = 0; c < CH; ++c) {
    const float4* x4 = (const float4*)&xc[((size_t)b * CH + c) * NMODE + j0];
    float4 v0 = x4[0], v1 = x4[1];
    float xrv[4] = {v0.x, v0.z, v1.x, v1.z};
    float xiv[4] = {v0.y, v0.w, v1.y, v1.w};
    float w[8];
    #pragma unroll
    for (int pp = 0; pp < 8; ++pp) w[pp] = wT[c][ty * 8 + pp];
    #pragma unroll
    for (int jj = 0; jj < 4; ++jj)
      #pragma unroll
      for (int pp = 0; pp < 8; ++pp) {
        accR[jj][pp] += w[pp] * xrv[jj];
        accI[jj][pp] += w[pp] * xiv[jj];
      }
  }
  #pragma unroll
  for (int pp = 0; pp < 8; ++pp) {
    int p = ty * 8 + pp;
    float4* o4 = (float4*)&hc[((size_t)b * CH + p) * NMODE + j0];
    o4[0] = make_float4(accR[0][pp], accI[0][pp], accR[1][pp], accI[1][pp]);
    o4[1] = make_float4(accR[2][pp], accI[2][pp], accR[3][pp], accI[3][pp]);
  }
}

// ---------------- K5: fused iDFT + bias + gelu + pw2, p-group partials ----------------
__global__ __launch_bounds__(256) void k_idft_partial(const float2* __restrict__ hc,
                                                      const float* __restrict__ pb1,
                                                      const float* __restrict__ pw2,
                                                      float* __restrict__ partial) {
  __shared__ float2 tw[DIM];                  // (cos, sin) 1 KB
  __shared__ float2 hfs[NMODE];               // 16 KB
  __shared__ float2 sbuf[KY][9];              // padded, ~2.3 KB
  int bid = blockIdx.x;
  int b = bid >> 7, pg = (bid >> 4) & 7, xs = bid & 15;
  int x0 = xs * 8;
  int t = threadIdx.x;
  if (t < 128) {
    float ang = (float)(2.0 * M_PI) * (float)t / 128.0f;
    tw[t] = make_float2(cosf(ang), sinf(ang));
  }
  __syncthreads();
  int y = t & 127, xh = t >> 7;
  float Cr[KY], Sr[KY];
  #pragma unroll
  for (int ky = 0; ky < KY; ++ky) {
    float2 w = tw[(ky * y) & 127];
    float wk = (ky == 0) ? 1.f : 2.f;
    Cr[ky] = wk * w.x;
    Sr[ky] = -wk * w.y;
  }
  int kyA = t & 31, xiA = t >> 5;
  int xA = x0 + xiA;
  float res[4] = {0.f, 0.f, 0.f, 0.f};
  for (int pp = 0; pp < PPG; ++pp) {
    int p = pg * PPG + pp;
    __syncthreads();
    {
      const float4* src = (const float4*)&hc[((size_t)b * CH + p) * NMODE];
      float4* dst = (float4*)hfs;
      for (int e = t; e < NMODE / 2; e += 256) dst[e] = src[e];
    }
    __syncthreads();
    {
      float ar = 0.f, ai = 0.f;
      #pragma unroll
      for (int uu = 0; uu < U; ++uu) {
        int kx = (uu < 32) ? uu : (uu + 64);
        int tt = (kx * xA) & 127;
        float2 w = tw[tt];
        float2 v = hfs[uu * KY + kyA];
        ar += v.x * w.x - v.y * w.y;
        ai += v.x * w.y + v.y * w.x;
      }
      sbuf[kyA][xiA] = make_float2(ar, ai);
    }
    __syncthreads();
    float pb = pb1[p], pw = pw2[p];
    #pragma unroll
    for (int k = 0; k < 4; ++k) {
      int xi = k * 2 + xh;
      float acc = 0.f;
      #pragma unroll
      for (int ky = 0; ky < KY; ++ky) {
        float2 sv = sbuf[ky][xi];
        acc += sv.x * Cr[ky] + sv.y * Sr[ky];
      }
      float h = acc * (1.f / 16384.f) + pb;
      float g = 0.5f * h * (1.f + tanhf(0.7978845608028654f * (h + 0.044715f * h * h * h)));
      res[k] += pw * g;
    }
  }
  #pragma unroll
  for (int k = 0; k < 4; ++k) {
    int x = x0 + k * 2 + xh;
    partial[((size_t)pg * B + b) * N2 + x * DIM + y] = res[k];
  }
}

// ---------------- K6: reduce p-group partials + pb2 ----------------
__global__ __launch_bounds__(256) void k_reduce(const float* __restrict__ partial,
                                                const float* __restrict__ pb2,
                                                float* __restrict__ outp) {
  int idx = blockIdx.x * 256 + threadIdx.x;   // B*N2 = 262144
  if (idx >= B * N2) return;
  float s = pb2[0];
  #pragma unroll
  for (int pg = 0; pg < PG; ++pg) s += partial[(size_t)pg * B * N2 + idx];
  outp[idx] = s;
}

extern "C" void kernel_launch(void* const* d_in, const int* in_sizes, int n_in,
                              void* d_out, int out_size, void* d_ws, size_t ws_size,
                              hipStream_t stream) {
  const float* z   = (const float*)d_in[0];
  const float* lw  = (const float*)d_in[1];
  const float* lb  = (const float*)d_in[2];
  const float* wr1 = (const float*)d_in[3];
  const float* wi1 = (const float*)d_in[4];
  const float* wr2 = (const float*)d_in[5];
  const float* wi2 = (const float*)d_in[6];
  const float* pw1 = (const float*)d_in[7];
  const float* pb1 = (const float*)d_in[8];
  const float* pw2 = (const float*)d_in[9];
  const float* pb2 = (const float*)d_in[10];
  float* out = (float*)d_out;
  float* ws = (float*)d_ws;

  float* zfr = ws;
  float* zfi = zfr + 32768;
  float2* Ac = (float2*)(ws + 65536);
  float2* Bc = Ac + (size_t)B * CH * NMODE;

  k_zf<<<B, 256, 0, stream>>>(z, zfr, zfi);
  k_lift<<<(B * CH * NMODE) / 256, 256, 0, stream>>>(zfr, zfi, lw, lb, Ac);

  const size_t WSTRIDE = (size_t)CH * CH * MODES * MODES;
  float2 *ir = Ac, *oc = Bc;
  for (int l = 0; l < NLAYERS; ++l) {
    k_spec<<<512, 256, 0, stream>>>(ir,
                                    wr1 + l * WSTRIDE, wi1 + l * WSTRIDE,
                                    wr2 + l * WSTRIDE, wi2 + l * WSTRIDE,
                                    oc);
    if (l < NLAYERS - 1)
      k_proj0<<<(B * CH * 33 + 255) / 256, 256, 0, stream>>>(oc);
    float2* tmp = ir; ir = oc; oc = tmp;
  }
  k_pw1<<<512, 256, 0, stream>>>(ir, pw1, oc);
  float* partial = (float*)ir;
  k_idft_partial<<<B * PG * 16, 256, 0, stream>>>(oc, pb1, pw2, partial);
  k_reduce<<<(B * N2) / 256, 256, 0, stream>>>(partial, pb2, out);
}